// Round 6
// baseline (104670.288 us; speedup 1.0000x reference)
//
#include <hip/hip_runtime.h>

// GRUModel: 2-layer GRU (T=16384, IN=512, H=1024) + BatchNorm(train) + FC(H->1)
//
// Persistent kernel, 128 blocks (64 layer0 + 64 layer1), 4 waves each; every
// wave owns 4 contiguous channels end-to-end (weights in VGPRs as f16 pairs,
// v_dot2_f32_f16). No __syncthreads, no LDS: wave-local butterfly reduction,
// gates computed redundantly in all lanes, one atomic u64 store per wave
// (4 channels packed f16). Cross-block exchange via AGENT-scope relaxed
// atomics on ws; consumers poll their own u64 granules against the f16-NaN
// sentinel 0x7F7F7F7F (memset 0x7F). Producers store whole u64s atomically,
// so checking the low u32 suffices. Gate outputs are never NaN => data==flag.
//
// ROUND-6 CHANGE (theory v3: two SERIAL far-memory handoffs per step are the
// period): FETCH_SIZE ~720MB == spin traffic => agent-scope polls are serviced
// past L2 (~0.3-0.4us round trip). Baseline layer-1 paid h1-detect and
// h2-detect SERIALLY (control-dependent do-while loops). Fix, minimal diff:
//   layer 1: ONE combined poll loop issues all 8 loads (h1[t] + h2[t-1])
//            back-to-back -> the two round trips pipeline; saves ~1 handoff.
//   layer 0: issue the 4 poll loads BEFORE the x-part dots, check after ->
//            first round trip hides under independent VALU work.
// Rounds 4/5 (wave-role split / LDS broadcast polling) both regressed:
// barriers + LDS put the full dot chain on the critical path and bank
// conflicts (1.5e8) added cycles; reverted entirely.

#define TT 16384
#define IND 512
#define HD 1024

typedef _Float16 h2_t __attribute__((ext_vector_type(2)));
typedef unsigned long long u64;

static __device__ __forceinline__ float fdot2f(h2_t a, h2_t b, float c) {
  return __builtin_amdgcn_fdot2(a, b, c, false);
}
static __device__ __forceinline__ h2_t cvt2(float a, float b) {
  h2_t r; r.x = (_Float16)a; r.y = (_Float16)b; return r;
}
static __device__ __forceinline__ float sigm(float v) { return 1.f / (1.f + __expf(-v)); }
static __device__ __forceinline__ float tanh_f(float v) {
  v = fminf(fmaxf(v, -15.f), 15.f);
  float e = __expf(2.f * v);
  return (e - 1.f) / (e + 1.f);
}

// Reduce 4 per-lane partials across 64 lanes. Returns (R,Z,Nx,Nh) totals in
// all lanes. 11 DS ops instead of 24 (pair-merge butterfly).
static __device__ __forceinline__ float4 reduce4(float aR, float aZ, float aNx,
                                                 float aNh, int lane) {
  const bool s1 = lane & 1;
  float x1 = s1 ? aZ : aR, y1 = s1 ? aR : aZ;
  x1 += __shfl_xor(y1, 1);
  float x2 = s1 ? aNh : aNx, y2 = s1 ? aNx : aNh;
  x2 += __shfl_xor(y2, 1);
  const bool s2 = lane & 2;
  float z = s2 ? x2 : x1, w = s2 ? x1 : x2;
  z += __shfl_xor(w, 2);
  z += __shfl_xor(z, 4);
  z += __shfl_xor(z, 8);
  z += __shfl_xor(z, 16);
  z += __shfl_xor(z, 32);
  // lane%4==0 holds sumR, ==1 sumZ, ==2 sumNx, ==3 sumNh
  return make_float4(__shfl(z, 0), __shfl(z, 1), __shfl(z, 2), __shfl(z, 3));
}

static __device__ __forceinline__ u64 pack4(float h0, float h1,
                                            float h2, float h3) {
  unsigned lo = (unsigned)__builtin_bit_cast(unsigned short, (_Float16)h0) |
                ((unsigned)__builtin_bit_cast(unsigned short, (_Float16)h1) << 16);
  unsigned hi = (unsigned)__builtin_bit_cast(unsigned short, (_Float16)h2) |
                ((unsigned)__builtin_bit_cast(unsigned short, (_Float16)h3) << 16);
  return (u64)lo | ((u64)hi << 32);
}

static __device__ __forceinline__ void unpack8(const u64 hv[4], h2_t hh[8]) {
#pragma unroll
  for (int i = 0; i < 4; ++i) {
    hh[2 * i]     = __builtin_bit_cast(h2_t, (unsigned)hv[i]);
    hh[2 * i + 1] = __builtin_bit_cast(h2_t, (unsigned)(hv[i] >> 32));
  }
}

__launch_bounds__(256, 1)
__global__ void gru_persistent(
    const float* __restrict__ x,
    const float* __restrict__ wih0, const float* __restrict__ whh0,
    const float* __restrict__ bih0, const float* __restrict__ bhh0,
    const float* __restrict__ wih1, const float* __restrict__ whh1,
    const float* __restrict__ bih1, const float* __restrict__ bhh1,
    u64* h1u, u64* h2u, float* sums)
{
  const int bid = blockIdx.x;
  const int tid = threadIdx.x;
  const int wave = tid >> 6;
  const int lane = tid & 63;

  if (bid < 64) {
    // ---------------- layer 0 : wave owns channels ch..ch+3 ----------------
    const int ch = bid * 16 + wave * 4;
    h2_t Wx[4][3][4];   // x-part: 8 f16 per gate per channel
    h2_t Wh[4][3][8];   // h-part: 16 f16 per gate per channel
    float bRv[4], bZv[4], bNxv[4], bNhv[4];
#pragma unroll
    for (int cc = 0; cc < 4; ++cc) {
      const int c = ch + cc;
#pragma unroll
      for (int g = 0; g < 3; ++g) {
        const float* pr = wih0 + (size_t)(g * HD + c) * IND + 8 * lane;
#pragma unroll
        for (int j = 0; j < 4; ++j) Wx[cc][g][j] = cvt2(pr[2 * j], pr[2 * j + 1]);
        const float* ph = whh0 + (size_t)(g * HD + c) * HD + 16 * lane;
#pragma unroll
        for (int j = 0; j < 8; ++j) Wh[cc][g][j] = cvt2(ph[2 * j], ph[2 * j + 1]);
      }
      bRv[cc]  = bih0[c] + bhh0[c];
      bZv[cc]  = bih0[HD + c] + bhh0[HD + c];
      bNxv[cc] = bih0[2 * HD + c];
      bNhv[cc] = bhh0[2 * HD + c];
    }
    float hprev[4] = {0.f, 0.f, 0.f, 0.f};
    // software-pipelined x row
    const float* px0 = x + 8 * lane;
    float4 xa = *(const float4*)px0;
    float4 xb = *(const float4*)(px0 + 4);
    for (int t = 0; t < TT; ++t) {
      // FIRST-SHOT poll loads issued before x-dots: round trip hides under
      // the independent VALU work below. Check (and re-poll) afterwards.
      const u64* p1 = h1u + (size_t)t * 256 + 4 * lane;
      u64 hv[4];
#pragma unroll
      for (int i = 0; i < 4; ++i)
        hv[i] = __hip_atomic_load(p1 + i, __ATOMIC_RELAXED, __HIP_MEMORY_SCOPE_AGENT);
      h2_t xv[4];
      xv[0] = cvt2(xa.x, xa.y); xv[1] = cvt2(xa.z, xa.w);
      xv[2] = cvt2(xb.x, xb.y); xv[3] = cvt2(xb.z, xb.w);
      if (t + 1 < TT) {
        const float* pn = x + (size_t)(t + 1) * IND + 8 * lane;
        xa = *(const float4*)pn;
        xb = *(const float4*)(pn + 4);
      }
      // x-part partials (independent of hv)
      float aR[4], aZ[4], aNx[4], aNh[4];
#pragma unroll
      for (int cc = 0; cc < 4; ++cc) {
        float r = 0.f, z = 0.f, n = 0.f;
#pragma unroll
        for (int j = 0; j < 4; ++j) {
          r = fdot2f(Wx[cc][0][j], xv[j], r);
          z = fdot2f(Wx[cc][1][j], xv[j], z);
          n = fdot2f(Wx[cc][2][j], xv[j], n);
        }
        aR[cc] = r; aZ[cc] = z; aNx[cc] = n; aNh[cc] = 0.f;
      }
      // now check the first-shot loads; re-poll only if needed
      bool ok = true;
#pragma unroll
      for (int i = 0; i < 4; ++i) ok = ok & ((unsigned)hv[i] != 0x7F7F7F7Fu);
      while (__any(!ok)) {
        ok = true;
#pragma unroll
        for (int i = 0; i < 4; ++i) {
          hv[i] = __hip_atomic_load(p1 + i, __ATOMIC_RELAXED, __HIP_MEMORY_SCOPE_AGENT);
          ok = ok & ((unsigned)hv[i] != 0x7F7F7F7Fu);
        }
      }
      h2_t hh[8];
      unpack8(hv, hh);
#pragma unroll
      for (int cc = 0; cc < 4; ++cc) {
        float r = aR[cc], z = aZ[cc], n = aNh[cc];
#pragma unroll
        for (int j = 0; j < 8; ++j) {
          r = fdot2f(Wh[cc][0][j], hh[j], r);
          z = fdot2f(Wh[cc][1][j], hh[j], z);
          n = fdot2f(Wh[cc][2][j], hh[j], n);
        }
        aR[cc] = r; aZ[cc] = z; aNh[cc] = n;
      }
      float hn[4];
#pragma unroll
      for (int cc = 0; cc < 4; ++cc) {
        float4 s = reduce4(aR[cc], aZ[cc], aNx[cc], aNh[cc], lane);
        float r = sigm(s.x + bRv[cc]);
        float zz = sigm(s.y + bZv[cc]);
        float n = tanh_f(s.z + bNxv[cc] + r * (s.w + bNhv[cc]));
        hn[cc] = (1.f - zz) * n + zz * hprev[cc];
        hprev[cc] = hn[cc];
      }
      if (lane == 0) {
        u64 pk = pack4(hn[0], hn[1], hn[2], hn[3]);
        __hip_atomic_store(h1u + (size_t)(t + 1) * 256 + (ch >> 2), pk,
                           __ATOMIC_RELAXED, __HIP_MEMORY_SCOPE_AGENT);
      }
    }
  } else {
    // ---------------- layer 1 : wave owns channels ch..ch+3 ----------------
    const int ch = (bid - 64) * 16 + wave * 4;
    // parts: 0=r_ih 1=r_hh 2=z_ih 3=z_hh 4=n_ih 5=n_hh ; 16-f16 slice each
    h2_t W[4][6][8];
    float bRv[4], bZv[4], bNxv[4], bNhv[4];
#pragma unroll
    for (int cc = 0; cc < 4; ++cc) {
      const int c = ch + cc;
#pragma unroll
      for (int g = 0; g < 3; ++g) {
        const float* pi = wih1 + (size_t)(g * HD + c) * HD + 16 * lane;
        const float* ph = whh1 + (size_t)(g * HD + c) * HD + 16 * lane;
#pragma unroll
        for (int j = 0; j < 8; ++j) {
          W[cc][2 * g][j]     = cvt2(pi[2 * j], pi[2 * j + 1]);
          W[cc][2 * g + 1][j] = cvt2(ph[2 * j], ph[2 * j + 1]);
        }
      }
      bRv[cc]  = bih1[c] + bhh1[c];
      bZv[cc]  = bih1[HD + c] + bhh1[HD + c];
      bNxv[cc] = bih1[2 * HD + c];
      bNhv[cc] = bhh1[2 * HD + c];
    }
    float hprev[4] = {0.f, 0.f, 0.f, 0.f};
    float ssum[4] = {0.f, 0.f, 0.f, 0.f};
    float ssq[4] = {0.f, 0.f, 0.f, 0.f};
    for (int t = 1; t <= TT; ++t) {
      // COMBINED poll: issue all 8 loads (h1[t-1] slot t AND h2[t-2] slot t-1)
      // back-to-back so the two far-memory round trips overlap. Re-polling an
      // already-clear granule is harmless (write-once data).
      const u64* p1 = h1u + (size_t)t * 256 + 4 * lane;
      const u64* p2 = h2u + (size_t)(t - 1) * 256 + 4 * lane;
      u64 va[4], vb[4];
      bool ok;
      do {
        ok = true;
#pragma unroll
        for (int i = 0; i < 4; ++i) {
          va[i] = __hip_atomic_load(p1 + i, __ATOMIC_RELAXED, __HIP_MEMORY_SCOPE_AGENT);
          vb[i] = __hip_atomic_load(p2 + i, __ATOMIC_RELAXED, __HIP_MEMORY_SCOPE_AGENT);
        }
#pragma unroll
        for (int i = 0; i < 4; ++i) {
          ok = ok & ((unsigned)va[i] != 0x7F7F7F7Fu)
                  & ((unsigned)vb[i] != 0x7F7F7F7Fu);
        }
      } while (__any(!ok));
      h2_t g1[8], g2[8];
      unpack8(va, g1);
      unpack8(vb, g2);
      float aR[4], aZ[4], aNx[4], aNh[4];
#pragma unroll
      for (int cc = 0; cc < 4; ++cc) {
        float r = 0.f, z = 0.f, n = 0.f;
#pragma unroll
        for (int j = 0; j < 8; ++j) {
          r = fdot2f(W[cc][0][j], g1[j], r);
          z = fdot2f(W[cc][2][j], g1[j], z);
          n = fdot2f(W[cc][4][j], g1[j], n);
        }
        aR[cc] = r; aZ[cc] = z; aNx[cc] = n; aNh[cc] = 0.f;
      }
#pragma unroll
      for (int cc = 0; cc < 4; ++cc) {
        float r = aR[cc], z = aZ[cc], n = aNh[cc];
#pragma unroll
        for (int j = 0; j < 8; ++j) {
          r = fdot2f(W[cc][1][j], g2[j], r);
          z = fdot2f(W[cc][3][j], g2[j], z);
          n = fdot2f(W[cc][5][j], g2[j], n);
        }
        aR[cc] = r; aZ[cc] = z; aNh[cc] = n;
      }
      float hn[4];
#pragma unroll
      for (int cc = 0; cc < 4; ++cc) {
        float4 s = reduce4(aR[cc], aZ[cc], aNx[cc], aNh[cc], lane);
        float r = sigm(s.x + bRv[cc]);
        float zz = sigm(s.y + bZv[cc]);
        float n = tanh_f(s.z + bNxv[cc] + r * (s.w + bNhv[cc]));
        hn[cc] = (1.f - zz) * n + zz * hprev[cc];
        hprev[cc] = hn[cc];
        ssum[cc] += hn[cc];
        ssq[cc] += hn[cc] * hn[cc];
      }
      if (lane == 0) {
        u64 pk = pack4(hn[0], hn[1], hn[2], hn[3]);
        __hip_atomic_store(h2u + (size_t)t * 256 + (ch >> 2), pk,
                           __ATOMIC_RELAXED, __HIP_MEMORY_SCOPE_AGENT);
      }
    }
    if (lane == 0) {
#pragma unroll
      for (int cc = 0; cc < 4; ++cc) {
        sums[ch + cc] = ssum[cc];
        sums[HD + ch + cc] = ssq[cc];
      }
    }
  }
}

// y[t] = K + sum_c h2[t,c]*A[c];  A = rsqrt(var+eps)*gamma*fc_w,
// K = fc_b + sum_c (beta*fc_w - mu*A)
__launch_bounds__(256)
__global__ void fc_bn_kernel(const unsigned* __restrict__ h2u, const float* __restrict__ sums,
                             const float* __restrict__ gamma, const float* __restrict__ beta,
                             const float* __restrict__ fcw, const float* __restrict__ fcb,
                             float* __restrict__ out)
{
  const int tid = threadIdx.x;
  const int wave = tid >> 6;
  const int lane = tid & 63;
  float A[16];
  float kp = 0.f;
#pragma unroll
  for (int j = 0; j < 16; ++j) {
    const int c = 16 * lane + j;
    float mu = sums[c] * (1.f / TT);
    float var = fmaxf(sums[HD + c] * (1.f / TT) - mu * mu, 0.f);
    float rs = rsqrtf(var + 1e-5f);
    float a = rs * gamma[c] * fcw[c];
    A[j] = a;
    kp += beta[c] * fcw[c] - mu * a;
  }
#pragma unroll
  for (int m = 32; m >= 1; m >>= 1) kp += __shfl_xor(kp, m);
  const float K = kp + fcb[0];
  const int tbase = (blockIdx.x * 4 + wave) * 16;
  for (int mm = 0; mm < 16; ++mm) {
    const int t = tbase + mm;
    const unsigned* p = h2u + (size_t)(t + 1) * 512 + 8 * lane;
    float d = 0.f;
#pragma unroll
    for (int j = 0; j < 8; ++j) {
      h2_t hp = __builtin_bit_cast(h2_t, p[j]);
      d += (float)hp.x * A[2 * j] + (float)hp.y * A[2 * j + 1];
    }
#pragma unroll
    for (int m = 32; m >= 1; m >>= 1) d += __shfl_xor(d, m);
    if (lane == 0) out[t] = K + d;
  }
}

extern "C" void kernel_launch(void* const* d_in, const int* in_sizes, int n_in,
                              void* d_out, int out_size, void* d_ws, size_t ws_size,
                              hipStream_t stream) {
  const float* x    = (const float*)d_in[0];
  const float* wih0 = (const float*)d_in[1];
  const float* whh0 = (const float*)d_in[2];
  const float* bih0 = (const float*)d_in[3];
  const float* bhh0 = (const float*)d_in[4];
  const float* wih1 = (const float*)d_in[5];
  const float* whh1 = (const float*)d_in[6];
  const float* bih1 = (const float*)d_in[7];
  const float* bhh1 = (const float*)d_in[8];
  const float* gamma = (const float*)d_in[9];
  const float* beta  = (const float*)d_in[10];
  const float* fcw   = (const float*)d_in[11];
  const float* fcb   = (const float*)d_in[12];

  const size_t HIST = (size_t)(TT + 1) * HD * 2;   // 33,556,480 B per history
  u64* h1u = (u64*)d_ws;
  u64* h2u = (u64*)((char*)d_ws + HIST);
  float* sums = (float*)((char*)d_ws + 2 * HIST);

  // slot 0 = h[-1] = 0 ; slots 1..TT = f16 NaN sentinel (0x7F7F)
  hipMemsetAsync(h1u, 0, (size_t)HD * 2, stream);
  hipMemsetAsync((char*)h1u + HD * 2, 0x7F, (size_t)TT * HD * 2, stream);
  hipMemsetAsync(h2u, 0, (size_t)HD * 2, stream);
  hipMemsetAsync((char*)h2u + HD * 2, 0x7F, (size_t)TT * HD * 2, stream);

  gru_persistent<<<128, 256, 0, stream>>>(x, wih0, whh0, bih0, bhh0,
                                          wih1, whh1, bih1, bhh1,
                                          h1u, h2u, sums);
  fc_bn_kernel<<<256, 256, 0, stream>>>((const unsigned*)h2u, sums, gamma, beta, fcw, fcb,
                                        (float*)d_out);
}

// Round 7
// 91342.090 us; speedup vs baseline: 1.1459x; 1.1459x over previous
//
#include <hip/hip_runtime.h>

// GRUModel: 2-layer GRU (T=16384, IN=512, H=1024) + BatchNorm(train) + FC(H->1)
//
// Persistent kernel, 128 blocks (64 layer0 + 64 layer1), 4 waves each; every
// wave owns 4 contiguous channels end-to-end (weights in VGPRs as f16 pairs,
// v_dot2_f32_f16). No __syncthreads, no LDS: wave-local butterfly reduction,
// gates computed redundantly in all lanes, one atomic u64 store per wave
// (4 channels packed f16). Cross-block exchange via AGENT-scope relaxed
// atomics on ws; consumers poll their own u64 granules against the f16-NaN
// sentinel 0x7F7F7F7F (memset 0x7F). Producers store whole u64s atomically,
// so checking the low u32 suffices. Gate outputs are never NaN => data==flag.
//
// ROUND-7 (theory v4: spin-load CONGESTION sets the handoff latency).
// Empirical law from R4/R5/R6: dur tracks agent-scope poll issue volume
// (R6: 2x loads/spin-iter -> FETCH 720MB->2.5GB, dur 53.6->104.7ms).
// This round STRICTLY REDUCES spin volume vs the 53.6ms baseline with zero
// structural change: per-granule MASKED re-polling (only granules still
// showing the sentinel are re-read; cleared ones are exec-masked off).
// Steady-state spin iterations touch only straggler lines (~3-4x less
// traffic). Layer-1 polls stay SERIAL (h1 then h2) - the R6 combined loop
// is reverted. Layer-0 issues its first-shot poll before the x-dots
// (traffic-neutral latency hiding). Loads are clustered before checks so
// each re-poll iteration pays ONE vmcnt wait.

#define TT 16384
#define IND 512
#define HD 1024

typedef _Float16 h2_t __attribute__((ext_vector_type(2)));
typedef unsigned long long u64;

static __device__ __forceinline__ float fdot2f(h2_t a, h2_t b, float c) {
  return __builtin_amdgcn_fdot2(a, b, c, false);
}
static __device__ __forceinline__ h2_t cvt2(float a, float b) {
  h2_t r; r.x = (_Float16)a; r.y = (_Float16)b; return r;
}
static __device__ __forceinline__ float sigm(float v) { return 1.f / (1.f + __expf(-v)); }
static __device__ __forceinline__ float tanh_f(float v) {
  v = fminf(fmaxf(v, -15.f), 15.f);
  float e = __expf(2.f * v);
  return (e - 1.f) / (e + 1.f);
}

// Reduce 4 per-lane partials across 64 lanes. Returns (R,Z,Nx,Nh) totals in
// all lanes. 11 DS ops instead of 24 (pair-merge butterfly).
static __device__ __forceinline__ float4 reduce4(float aR, float aZ, float aNx,
                                                 float aNh, int lane) {
  const bool s1 = lane & 1;
  float x1 = s1 ? aZ : aR, y1 = s1 ? aR : aZ;
  x1 += __shfl_xor(y1, 1);
  float x2 = s1 ? aNh : aNx, y2 = s1 ? aNx : aNh;
  x2 += __shfl_xor(y2, 1);
  const bool s2 = lane & 2;
  float z = s2 ? x2 : x1, w = s2 ? x1 : x2;
  z += __shfl_xor(w, 2);
  z += __shfl_xor(z, 4);
  z += __shfl_xor(z, 8);
  z += __shfl_xor(z, 16);
  z += __shfl_xor(z, 32);
  // lane%4==0 holds sumR, ==1 sumZ, ==2 sumNx, ==3 sumNh
  return make_float4(__shfl(z, 0), __shfl(z, 1), __shfl(z, 2), __shfl(z, 3));
}

static __device__ __forceinline__ u64 pack4(float h0, float h1,
                                            float h2, float h3) {
  unsigned lo = (unsigned)__builtin_bit_cast(unsigned short, (_Float16)h0) |
                ((unsigned)__builtin_bit_cast(unsigned short, (_Float16)h1) << 16);
  unsigned hi = (unsigned)__builtin_bit_cast(unsigned short, (_Float16)h2) |
                ((unsigned)__builtin_bit_cast(unsigned short, (_Float16)h3) << 16);
  return (u64)lo | ((u64)hi << 32);
}

static __device__ __forceinline__ void unpack8(const u64 hv[4], h2_t hh[8]) {
#pragma unroll
  for (int i = 0; i < 4; ++i) {
    hh[2 * i]     = __builtin_bit_cast(h2_t, (unsigned)hv[i]);
    hh[2 * i + 1] = __builtin_bit_cast(h2_t, (unsigned)(hv[i] >> 32));
  }
}

// Masked re-poll: given first-shot values hv[], re-read ONLY granules still
// showing the sentinel. Cleared granules/lanes are exec-masked off, cutting
// steady-state spin traffic. Loads are clustered before checks (one vmcnt
// wait per iteration).
static __device__ __forceinline__ void poll4_finish(const u64* p, u64 hv[4]) {
  bool ok[4];
#pragma unroll
  for (int i = 0; i < 4; ++i) ok[i] = ((unsigned)hv[i] != 0x7F7F7F7Fu);
  bool all = ok[0] & ok[1] & ok[2] & ok[3];
  while (__any(!all)) {
#pragma unroll
    for (int i = 0; i < 4; ++i)
      if (!ok[i])
        hv[i] = __hip_atomic_load(p + i, __ATOMIC_RELAXED, __HIP_MEMORY_SCOPE_AGENT);
#pragma unroll
    for (int i = 0; i < 4; ++i)
      ok[i] = ok[i] | ((unsigned)hv[i] != 0x7F7F7F7Fu);
    all = ok[0] & ok[1] & ok[2] & ok[3];
  }
}

static __device__ __forceinline__ void poll4(const u64* p, u64 hv[4]) {
#pragma unroll
  for (int i = 0; i < 4; ++i)
    hv[i] = __hip_atomic_load(p + i, __ATOMIC_RELAXED, __HIP_MEMORY_SCOPE_AGENT);
  poll4_finish(p, hv);
}

__launch_bounds__(256, 1)
__global__ void gru_persistent(
    const float* __restrict__ x,
    const float* __restrict__ wih0, const float* __restrict__ whh0,
    const float* __restrict__ bih0, const float* __restrict__ bhh0,
    const float* __restrict__ wih1, const float* __restrict__ whh1,
    const float* __restrict__ bih1, const float* __restrict__ bhh1,
    u64* h1u, u64* h2u, float* sums)
{
  const int bid = blockIdx.x;
  const int tid = threadIdx.x;
  const int wave = tid >> 6;
  const int lane = tid & 63;

  if (bid < 64) {
    // ---------------- layer 0 : wave owns channels ch..ch+3 ----------------
    const int ch = bid * 16 + wave * 4;
    h2_t Wx[4][3][4];   // x-part: 8 f16 per gate per channel
    h2_t Wh[4][3][8];   // h-part: 16 f16 per gate per channel
    float bRv[4], bZv[4], bNxv[4], bNhv[4];
#pragma unroll
    for (int cc = 0; cc < 4; ++cc) {
      const int c = ch + cc;
#pragma unroll
      for (int g = 0; g < 3; ++g) {
        const float* pr = wih0 + (size_t)(g * HD + c) * IND + 8 * lane;
#pragma unroll
        for (int j = 0; j < 4; ++j) Wx[cc][g][j] = cvt2(pr[2 * j], pr[2 * j + 1]);
        const float* ph = whh0 + (size_t)(g * HD + c) * HD + 16 * lane;
#pragma unroll
        for (int j = 0; j < 8; ++j) Wh[cc][g][j] = cvt2(ph[2 * j], ph[2 * j + 1]);
      }
      bRv[cc]  = bih0[c] + bhh0[c];
      bZv[cc]  = bih0[HD + c] + bhh0[HD + c];
      bNxv[cc] = bih0[2 * HD + c];
      bNhv[cc] = bhh0[2 * HD + c];
    }
    float hprev[4] = {0.f, 0.f, 0.f, 0.f};
    // software-pipelined x row
    const float* px0 = x + 8 * lane;
    float4 xa = *(const float4*)px0;
    float4 xb = *(const float4*)(px0 + 4);
    for (int t = 0; t < TT; ++t) {
      // first-shot poll loads issued BEFORE the x-dots: the round trip hides
      // under independent VALU work (traffic-neutral latency hiding).
      const u64* p1 = h1u + (size_t)t * 256 + 4 * lane;
      u64 hv[4];
#pragma unroll
      for (int i = 0; i < 4; ++i)
        hv[i] = __hip_atomic_load(p1 + i, __ATOMIC_RELAXED, __HIP_MEMORY_SCOPE_AGENT);
      h2_t xv[4];
      xv[0] = cvt2(xa.x, xa.y); xv[1] = cvt2(xa.z, xa.w);
      xv[2] = cvt2(xb.x, xb.y); xv[3] = cvt2(xb.z, xb.w);
      if (t + 1 < TT) {
        const float* pn = x + (size_t)(t + 1) * IND + 8 * lane;
        xa = *(const float4*)pn;
        xb = *(const float4*)(pn + 4);
      }
      // x-part partials (independent of hv)
      float aR[4], aZ[4], aNx[4], aNh[4];
#pragma unroll
      for (int cc = 0; cc < 4; ++cc) {
        float r = 0.f, z = 0.f, n = 0.f;
#pragma unroll
        for (int j = 0; j < 4; ++j) {
          r = fdot2f(Wx[cc][0][j], xv[j], r);
          z = fdot2f(Wx[cc][1][j], xv[j], z);
          n = fdot2f(Wx[cc][2][j], xv[j], n);
        }
        aR[cc] = r; aZ[cc] = z; aNx[cc] = n; aNh[cc] = 0.f;
      }
      // finish the poll: masked re-reads of straggler granules only
      poll4_finish(p1, hv);
      h2_t hh[8];
      unpack8(hv, hh);
#pragma unroll
      for (int cc = 0; cc < 4; ++cc) {
        float r = aR[cc], z = aZ[cc], n = aNh[cc];
#pragma unroll
        for (int j = 0; j < 8; ++j) {
          r = fdot2f(Wh[cc][0][j], hh[j], r);
          z = fdot2f(Wh[cc][1][j], hh[j], z);
          n = fdot2f(Wh[cc][2][j], hh[j], n);
        }
        aR[cc] = r; aZ[cc] = z; aNh[cc] = n;
      }
      float hn[4];
#pragma unroll
      for (int cc = 0; cc < 4; ++cc) {
        float4 s = reduce4(aR[cc], aZ[cc], aNx[cc], aNh[cc], lane);
        float r = sigm(s.x + bRv[cc]);
        float zz = sigm(s.y + bZv[cc]);
        float n = tanh_f(s.z + bNxv[cc] + r * (s.w + bNhv[cc]));
        hn[cc] = (1.f - zz) * n + zz * hprev[cc];
        hprev[cc] = hn[cc];
      }
      if (lane == 0) {
        u64 pk = pack4(hn[0], hn[1], hn[2], hn[3]);
        __hip_atomic_store(h1u + (size_t)(t + 1) * 256 + (ch >> 2), pk,
                           __ATOMIC_RELAXED, __HIP_MEMORY_SCOPE_AGENT);
      }
    }
  } else {
    // ---------------- layer 1 : wave owns channels ch..ch+3 ----------------
    const int ch = (bid - 64) * 16 + wave * 4;
    // parts: 0=r_ih 1=r_hh 2=z_ih 3=z_hh 4=n_ih 5=n_hh ; 16-f16 slice each
    h2_t W[4][6][8];
    float bRv[4], bZv[4], bNxv[4], bNhv[4];
#pragma unroll
    for (int cc = 0; cc < 4; ++cc) {
      const int c = ch + cc;
#pragma unroll
      for (int g = 0; g < 3; ++g) {
        const float* pi = wih1 + (size_t)(g * HD + c) * HD + 16 * lane;
        const float* ph = whh1 + (size_t)(g * HD + c) * HD + 16 * lane;
#pragma unroll
        for (int j = 0; j < 8; ++j) {
          W[cc][2 * g][j]     = cvt2(pi[2 * j], pi[2 * j + 1]);
          W[cc][2 * g + 1][j] = cvt2(ph[2 * j], ph[2 * j + 1]);
        }
      }
      bRv[cc]  = bih1[c] + bhh1[c];
      bZv[cc]  = bih1[HD + c] + bhh1[HD + c];
      bNxv[cc] = bih1[2 * HD + c];
      bNhv[cc] = bhh1[2 * HD + c];
    }
    float hprev[4] = {0.f, 0.f, 0.f, 0.f};
    float ssum[4] = {0.f, 0.f, 0.f, 0.f};
    float ssq[4] = {0.f, 0.f, 0.f, 0.f};
    for (int t = 1; t <= TT; ++t) {
      // poll h1[t-1] (slot t) FIRST — layer0 free-runs ahead, usually ready;
      // masked spin costs ~1 iteration.
      const u64* p1 = h1u + (size_t)t * 256 + 4 * lane;
      u64 va[4];
      poll4(p1, va);
      h2_t g1[8];
      unpack8(va, g1);
      float aR[4], aZ[4], aNx[4], aNh[4];
#pragma unroll
      for (int cc = 0; cc < 4; ++cc) {
        float r = 0.f, z = 0.f, n = 0.f;
#pragma unroll
        for (int j = 0; j < 8; ++j) {
          r = fdot2f(W[cc][0][j], g1[j], r);
          z = fdot2f(W[cc][2][j], g1[j], z);
          n = fdot2f(W[cc][4][j], g1[j], n);
        }
        aR[cc] = r; aZ[cc] = z; aNx[cc] = n; aNh[cc] = 0.f;
      }
      // poll h2[t-2] (slot t-1) — the binding recurrence; masked spin so
      // steady-state iterations re-read only straggler granules.
      const u64* p2 = h2u + (size_t)(t - 1) * 256 + 4 * lane;
      u64 vb[4];
      poll4(p2, vb);
      h2_t g2[8];
      unpack8(vb, g2);
#pragma unroll
      for (int cc = 0; cc < 4; ++cc) {
        float r = aR[cc], z = aZ[cc], n = aNh[cc];
#pragma unroll
        for (int j = 0; j < 8; ++j) {
          r = fdot2f(W[cc][1][j], g2[j], r);
          z = fdot2f(W[cc][3][j], g2[j], z);
          n = fdot2f(W[cc][5][j], g2[j], n);
        }
        aR[cc] = r; aZ[cc] = z; aNh[cc] = n;
      }
      float hn[4];
#pragma unroll
      for (int cc = 0; cc < 4; ++cc) {
        float4 s = reduce4(aR[cc], aZ[cc], aNx[cc], aNh[cc], lane);
        float r = sigm(s.x + bRv[cc]);
        float zz = sigm(s.y + bZv[cc]);
        float n = tanh_f(s.z + bNxv[cc] + r * (s.w + bNhv[cc]));
        hn[cc] = (1.f - zz) * n + zz * hprev[cc];
        hprev[cc] = hn[cc];
        ssum[cc] += hn[cc];
        ssq[cc] += hn[cc] * hn[cc];
      }
      if (lane == 0) {
        u64 pk = pack4(hn[0], hn[1], hn[2], hn[3]);
        __hip_atomic_store(h2u + (size_t)t * 256 + (ch >> 2), pk,
                           __ATOMIC_RELAXED, __HIP_MEMORY_SCOPE_AGENT);
      }
    }
    if (lane == 0) {
#pragma unroll
      for (int cc = 0; cc < 4; ++cc) {
        sums[ch + cc] = ssum[cc];
        sums[HD + ch + cc] = ssq[cc];
      }
    }
  }
}

// y[t] = K + sum_c h2[t,c]*A[c];  A = rsqrt(var+eps)*gamma*fc_w,
// K = fc_b + sum_c (beta*fc_w - mu*A)
__launch_bounds__(256)
__global__ void fc_bn_kernel(const unsigned* __restrict__ h2u, const float* __restrict__ sums,
                             const float* __restrict__ gamma, const float* __restrict__ beta,
                             const float* __restrict__ fcw, const float* __restrict__ fcb,
                             float* __restrict__ out)
{
  const int tid = threadIdx.x;
  const int wave = tid >> 6;
  const int lane = tid & 63;
  float A[16];
  float kp = 0.f;
#pragma unroll
  for (int j = 0; j < 16; ++j) {
    const int c = 16 * lane + j;
    float mu = sums[c] * (1.f / TT);
    float var = fmaxf(sums[HD + c] * (1.f / TT) - mu * mu, 0.f);
    float rs = rsqrtf(var + 1e-5f);
    float a = rs * gamma[c] * fcw[c];
    A[j] = a;
    kp += beta[c] * fcw[c] - mu * a;
  }
#pragma unroll
  for (int m = 32; m >= 1; m >>= 1) kp += __shfl_xor(kp, m);
  const float K = kp + fcb[0];
  const int tbase = (blockIdx.x * 4 + wave) * 16;
  for (int mm = 0; mm < 16; ++mm) {
    const int t = tbase + mm;
    const unsigned* p = h2u + (size_t)(t + 1) * 512 + 8 * lane;
    float d = 0.f;
#pragma unroll
    for (int j = 0; j < 8; ++j) {
      h2_t hp = __builtin_bit_cast(h2_t, p[j]);
      d += (float)hp.x * A[2 * j] + (float)hp.y * A[2 * j + 1];
    }
#pragma unroll
    for (int m = 32; m >= 1; m >>= 1) d += __shfl_xor(d, m);
    if (lane == 0) out[t] = K + d;
  }
}

extern "C" void kernel_launch(void* const* d_in, const int* in_sizes, int n_in,
                              void* d_out, int out_size, void* d_ws, size_t ws_size,
                              hipStream_t stream) {
  const float* x    = (const float*)d_in[0];
  const float* wih0 = (const float*)d_in[1];
  const float* whh0 = (const float*)d_in[2];
  const float* bih0 = (const float*)d_in[3];
  const float* bhh0 = (const float*)d_in[4];
  const float* wih1 = (const float*)d_in[5];
  const float* whh1 = (const float*)d_in[6];
  const float* bih1 = (const float*)d_in[7];
  const float* bhh1 = (const float*)d_in[8];
  const float* gamma = (const float*)d_in[9];
  const float* beta  = (const float*)d_in[10];
  const float* fcw   = (const float*)d_in[11];
  const float* fcb   = (const float*)d_in[12];

  const size_t HIST = (size_t)(TT + 1) * HD * 2;   // 33,556,480 B per history
  u64* h1u = (u64*)d_ws;
  u64* h2u = (u64*)((char*)d_ws + HIST);
  float* sums = (float*)((char*)d_ws + 2 * HIST);

  // slot 0 = h[-1] = 0 ; slots 1..TT = f16 NaN sentinel (0x7F7F)
  hipMemsetAsync(h1u, 0, (size_t)HD * 2, stream);
  hipMemsetAsync((char*)h1u + HD * 2, 0x7F, (size_t)TT * HD * 2, stream);
  hipMemsetAsync(h2u, 0, (size_t)HD * 2, stream);
  hipMemsetAsync((char*)h2u + HD * 2, 0x7F, (size_t)TT * HD * 2, stream);

  gru_persistent<<<128, 256, 0, stream>>>(x, wih0, whh0, bih0, bhh0,
                                          wih1, whh1, bih1, bhh1,
                                          h1u, h2u, sums);
  fc_bn_kernel<<<256, 256, 0, stream>>>((const unsigned*)h2u, sums, gamma, beta, fcw, fcb,
                                        (float*)d_out);
}

// Round 8
// 87515.515 us; speedup vs baseline: 1.1960x; 1.0437x over previous
//
#include <hip/hip_runtime.h>

// GRUModel: 2-layer GRU (T=16384, IN=512, H=1024) + BatchNorm(train) + FC(H->1)
//
// Persistent kernel, 128 blocks (64 layer0 + 64 layer1), 4 waves each; every
// wave owns 4 contiguous channels end-to-end (weights in VGPRs as f16 pairs,
// v_dot2_f32_f16). No __syncthreads, no LDS: wave-local butterfly reduction,
// gates computed redundantly in all lanes, one atomic u64 store per wave
// (4 channels packed f16). Cross-block exchange via AGENT-scope relaxed
// atomics on ws; consumers poll their own u64 granules against the f16-NaN
// sentinel 0x7F7F7F7F (memset 0x7F). Producers store whole u64s atomically,
// so checking the low u32 suffices. Gate outputs are never NaN => data==flag.
//
// ROUND-8. Empirical law from R4-R7 (all regressed): dur tracks agent-scope
// poll ISSUE VOLUME; the baseline all-4-reload do-while placed as late as
// possible is a local optimum for spin structure. The one remaining serial
// cost in baseline layer 1: the h1 round trip (~0.5us even when ready) is
// paid BEFORE the h2 spin starts. This round overlaps them WITHOUT adding
// any loads (R6's fatal flaw was reloading h1 inside the spin):
//   layer 1: issue h1's 4 loads ONCE, then run the h2 spin exactly as
//            baseline (all-4 reload of h2 only), then verify h1 (zero-iter
//            in the common case - layer0 free-runs ahead).
// Layer 0 is byte-identical to the 53.6ms baseline (R7's early first-shot
// reverted: it started spins before data could be visible).

#define TT 16384
#define IND 512
#define HD 1024

typedef _Float16 h2_t __attribute__((ext_vector_type(2)));
typedef unsigned long long u64;

static __device__ __forceinline__ float fdot2f(h2_t a, h2_t b, float c) {
  return __builtin_amdgcn_fdot2(a, b, c, false);
}
static __device__ __forceinline__ h2_t cvt2(float a, float b) {
  h2_t r; r.x = (_Float16)a; r.y = (_Float16)b; return r;
}
static __device__ __forceinline__ float sigm(float v) { return 1.f / (1.f + __expf(-v)); }
static __device__ __forceinline__ float tanh_f(float v) {
  v = fminf(fmaxf(v, -15.f), 15.f);
  float e = __expf(2.f * v);
  return (e - 1.f) / (e + 1.f);
}

// Reduce 4 per-lane partials across 64 lanes. Returns (R,Z,Nx,Nh) totals in
// all lanes. 11 DS ops instead of 24 (pair-merge butterfly).
static __device__ __forceinline__ float4 reduce4(float aR, float aZ, float aNx,
                                                 float aNh, int lane) {
  const bool s1 = lane & 1;
  float x1 = s1 ? aZ : aR, y1 = s1 ? aR : aZ;
  x1 += __shfl_xor(y1, 1);
  float x2 = s1 ? aNh : aNx, y2 = s1 ? aNx : aNh;
  x2 += __shfl_xor(y2, 1);
  const bool s2 = lane & 2;
  float z = s2 ? x2 : x1, w = s2 ? x1 : x2;
  z += __shfl_xor(w, 2);
  z += __shfl_xor(z, 4);
  z += __shfl_xor(z, 8);
  z += __shfl_xor(z, 16);
  z += __shfl_xor(z, 32);
  // lane%4==0 holds sumR, ==1 sumZ, ==2 sumNx, ==3 sumNh
  return make_float4(__shfl(z, 0), __shfl(z, 1), __shfl(z, 2), __shfl(z, 3));
}

static __device__ __forceinline__ u64 pack4(float h0, float h1,
                                            float h2, float h3) {
  unsigned lo = (unsigned)__builtin_bit_cast(unsigned short, (_Float16)h0) |
                ((unsigned)__builtin_bit_cast(unsigned short, (_Float16)h1) << 16);
  unsigned hi = (unsigned)__builtin_bit_cast(unsigned short, (_Float16)h2) |
                ((unsigned)__builtin_bit_cast(unsigned short, (_Float16)h3) << 16);
  return (u64)lo | ((u64)hi << 32);
}

static __device__ __forceinline__ void unpack8(const u64 hv[4], h2_t hh[8]) {
#pragma unroll
  for (int i = 0; i < 4; ++i) {
    hh[2 * i]     = __builtin_bit_cast(h2_t, (unsigned)hv[i]);
    hh[2 * i + 1] = __builtin_bit_cast(h2_t, (unsigned)(hv[i] >> 32));
  }
}

__launch_bounds__(256, 1)
__global__ void gru_persistent(
    const float* __restrict__ x,
    const float* __restrict__ wih0, const float* __restrict__ whh0,
    const float* __restrict__ bih0, const float* __restrict__ bhh0,
    const float* __restrict__ wih1, const float* __restrict__ whh1,
    const float* __restrict__ bih1, const float* __restrict__ bhh1,
    u64* h1u, u64* h2u, float* sums)
{
  const int bid = blockIdx.x;
  const int tid = threadIdx.x;
  const int wave = tid >> 6;
  const int lane = tid & 63;

  if (bid < 64) {
    // ---------------- layer 0 : wave owns channels ch..ch+3 ----------------
    const int ch = bid * 16 + wave * 4;
    h2_t Wx[4][3][4];   // x-part: 8 f16 per gate per channel
    h2_t Wh[4][3][8];   // h-part: 16 f16 per gate per channel
    float bRv[4], bZv[4], bNxv[4], bNhv[4];
#pragma unroll
    for (int cc = 0; cc < 4; ++cc) {
      const int c = ch + cc;
#pragma unroll
      for (int g = 0; g < 3; ++g) {
        const float* pr = wih0 + (size_t)(g * HD + c) * IND + 8 * lane;
#pragma unroll
        for (int j = 0; j < 4; ++j) Wx[cc][g][j] = cvt2(pr[2 * j], pr[2 * j + 1]);
        const float* ph = whh0 + (size_t)(g * HD + c) * HD + 16 * lane;
#pragma unroll
        for (int j = 0; j < 8; ++j) Wh[cc][g][j] = cvt2(ph[2 * j], ph[2 * j + 1]);
      }
      bRv[cc]  = bih0[c] + bhh0[c];
      bZv[cc]  = bih0[HD + c] + bhh0[HD + c];
      bNxv[cc] = bih0[2 * HD + c];
      bNhv[cc] = bhh0[2 * HD + c];
    }
    float hprev[4] = {0.f, 0.f, 0.f, 0.f};
    // software-pipelined x row
    const float* px0 = x + 8 * lane;
    float4 xa = *(const float4*)px0;
    float4 xb = *(const float4*)(px0 + 4);
    for (int t = 0; t < TT; ++t) {
      h2_t xv[4];
      xv[0] = cvt2(xa.x, xa.y); xv[1] = cvt2(xa.z, xa.w);
      xv[2] = cvt2(xb.x, xb.y); xv[3] = cvt2(xb.z, xb.w);
      if (t + 1 < TT) {
        const float* pn = x + (size_t)(t + 1) * IND + 8 * lane;
        xa = *(const float4*)pn;
        xb = *(const float4*)(pn + 4);
      }
      // x-part partials (off critical path)
      float aR[4], aZ[4], aNx[4], aNh[4];
#pragma unroll
      for (int cc = 0; cc < 4; ++cc) {
        float r = 0.f, z = 0.f, n = 0.f;
#pragma unroll
        for (int j = 0; j < 4; ++j) {
          r = fdot2f(Wx[cc][0][j], xv[j], r);
          z = fdot2f(Wx[cc][1][j], xv[j], z);
          n = fdot2f(Wx[cc][2][j], xv[j], n);
        }
        aR[cc] = r; aZ[cc] = z; aNx[cc] = n; aNh[cc] = 0.f;
      }
      // poll h1[t-1] (slot t; slot 0 pre-zeroed) — baseline form
      const u64* p1 = h1u + (size_t)t * 256 + 4 * lane;
      u64 hv[4];
      bool ok;
      do {
        ok = true;
#pragma unroll
        for (int i = 0; i < 4; ++i) {
          hv[i] = __hip_atomic_load(p1 + i, __ATOMIC_RELAXED, __HIP_MEMORY_SCOPE_AGENT);
          ok = ok & ((unsigned)hv[i] != 0x7F7F7F7Fu);
        }
      } while (__any(!ok));
      h2_t hh[8];
      unpack8(hv, hh);
#pragma unroll
      for (int cc = 0; cc < 4; ++cc) {
        float r = aR[cc], z = aZ[cc], n = aNh[cc];
#pragma unroll
        for (int j = 0; j < 8; ++j) {
          r = fdot2f(Wh[cc][0][j], hh[j], r);
          z = fdot2f(Wh[cc][1][j], hh[j], z);
          n = fdot2f(Wh[cc][2][j], hh[j], n);
        }
        aR[cc] = r; aZ[cc] = z; aNh[cc] = n;
      }
      float hn[4];
#pragma unroll
      for (int cc = 0; cc < 4; ++cc) {
        float4 s = reduce4(aR[cc], aZ[cc], aNx[cc], aNh[cc], lane);
        float r = sigm(s.x + bRv[cc]);
        float zz = sigm(s.y + bZv[cc]);
        float n = tanh_f(s.z + bNxv[cc] + r * (s.w + bNhv[cc]));
        hn[cc] = (1.f - zz) * n + zz * hprev[cc];
        hprev[cc] = hn[cc];
      }
      if (lane == 0) {
        u64 pk = pack4(hn[0], hn[1], hn[2], hn[3]);
        __hip_atomic_store(h1u + (size_t)(t + 1) * 256 + (ch >> 2), pk,
                           __ATOMIC_RELAXED, __HIP_MEMORY_SCOPE_AGENT);
      }
    }
  } else {
    // ---------------- layer 1 : wave owns channels ch..ch+3 ----------------
    const int ch = (bid - 64) * 16 + wave * 4;
    // parts: 0=r_ih 1=r_hh 2=z_ih 3=z_hh 4=n_ih 5=n_hh ; 16-f16 slice each
    h2_t W[4][6][8];
    float bRv[4], bZv[4], bNxv[4], bNhv[4];
#pragma unroll
    for (int cc = 0; cc < 4; ++cc) {
      const int c = ch + cc;
#pragma unroll
      for (int g = 0; g < 3; ++g) {
        const float* pi = wih1 + (size_t)(g * HD + c) * HD + 16 * lane;
        const float* ph = whh1 + (size_t)(g * HD + c) * HD + 16 * lane;
#pragma unroll
        for (int j = 0; j < 8; ++j) {
          W[cc][2 * g][j]     = cvt2(pi[2 * j], pi[2 * j + 1]);
          W[cc][2 * g + 1][j] = cvt2(ph[2 * j], ph[2 * j + 1]);
        }
      }
      bRv[cc]  = bih1[c] + bhh1[c];
      bZv[cc]  = bih1[HD + c] + bhh1[HD + c];
      bNxv[cc] = bih1[2 * HD + c];
      bNhv[cc] = bhh1[2 * HD + c];
    }
    float hprev[4] = {0.f, 0.f, 0.f, 0.f};
    float ssum[4] = {0.f, 0.f, 0.f, 0.f};
    float ssq[4] = {0.f, 0.f, 0.f, 0.f};
    for (int t = 1; t <= TT; ++t) {
      // OVERLAPPED HANDOFFS: issue h1[t-1] (slot t) loads ONCE (no reload in
      // spin), then spin on h2[t-2] (slot t-1) exactly as baseline. The two
      // LLC round trips overlap; total poll wait = max, not sum.
      const u64* p1 = h1u + (size_t)t * 256 + 4 * lane;
      const u64* p2 = h2u + (size_t)(t - 1) * 256 + 4 * lane;
      u64 va[4], vb[4];
#pragma unroll
      for (int i = 0; i < 4; ++i)
        va[i] = __hip_atomic_load(p1 + i, __ATOMIC_RELAXED, __HIP_MEMORY_SCOPE_AGENT);
      bool ok;
      do {
        ok = true;
#pragma unroll
        for (int i = 0; i < 4; ++i) {
          vb[i] = __hip_atomic_load(p2 + i, __ATOMIC_RELAXED, __HIP_MEMORY_SCOPE_AGENT);
          ok = ok & ((unsigned)vb[i] != 0x7F7F7F7Fu);
        }
      } while (__any(!ok));
      // verify h1 (layer0 free-runs ahead; this is zero-iteration in the
      // common case and costs no loads when already clear)
      ok = true;
#pragma unroll
      for (int i = 0; i < 4; ++i) ok = ok & ((unsigned)va[i] != 0x7F7F7F7Fu);
      while (__any(!ok)) {
        ok = true;
#pragma unroll
        for (int i = 0; i < 4; ++i) {
          va[i] = __hip_atomic_load(p1 + i, __ATOMIC_RELAXED, __HIP_MEMORY_SCOPE_AGENT);
          ok = ok & ((unsigned)va[i] != 0x7F7F7F7Fu);
        }
      }
      h2_t g1[8], g2[8];
      unpack8(va, g1);
      unpack8(vb, g2);
      float aR[4], aZ[4], aNx[4], aNh[4];
#pragma unroll
      for (int cc = 0; cc < 4; ++cc) {
        float r = 0.f, z = 0.f, n = 0.f;
#pragma unroll
        for (int j = 0; j < 8; ++j) {
          r = fdot2f(W[cc][0][j], g1[j], r);
          z = fdot2f(W[cc][2][j], g1[j], z);
          n = fdot2f(W[cc][4][j], g1[j], n);
        }
        aR[cc] = r; aZ[cc] = z; aNx[cc] = n; aNh[cc] = 0.f;
      }
#pragma unroll
      for (int cc = 0; cc < 4; ++cc) {
        float r = aR[cc], z = aZ[cc], n = aNh[cc];
#pragma unroll
        for (int j = 0; j < 8; ++j) {
          r = fdot2f(W[cc][1][j], g2[j], r);
          z = fdot2f(W[cc][3][j], g2[j], z);
          n = fdot2f(W[cc][5][j], g2[j], n);
        }
        aR[cc] = r; aZ[cc] = z; aNh[cc] = n;
      }
      float hn[4];
#pragma unroll
      for (int cc = 0; cc < 4; ++cc) {
        float4 s = reduce4(aR[cc], aZ[cc], aNx[cc], aNh[cc], lane);
        float r = sigm(s.x + bRv[cc]);
        float zz = sigm(s.y + bZv[cc]);
        float n = tanh_f(s.z + bNxv[cc] + r * (s.w + bNhv[cc]));
        hn[cc] = (1.f - zz) * n + zz * hprev[cc];
        hprev[cc] = hn[cc];
        ssum[cc] += hn[cc];
        ssq[cc] += hn[cc] * hn[cc];
      }
      if (lane == 0) {
        u64 pk = pack4(hn[0], hn[1], hn[2], hn[3]);
        __hip_atomic_store(h2u + (size_t)t * 256 + (ch >> 2), pk,
                           __ATOMIC_RELAXED, __HIP_MEMORY_SCOPE_AGENT);
      }
    }
    if (lane == 0) {
#pragma unroll
      for (int cc = 0; cc < 4; ++cc) {
        sums[ch + cc] = ssum[cc];
        sums[HD + ch + cc] = ssq[cc];
      }
    }
  }
}

// y[t] = K + sum_c h2[t,c]*A[c];  A = rsqrt(var+eps)*gamma*fc_w,
// K = fc_b + sum_c (beta*fc_w - mu*A)
__launch_bounds__(256)
__global__ void fc_bn_kernel(const unsigned* __restrict__ h2u, const float* __restrict__ sums,
                             const float* __restrict__ gamma, const float* __restrict__ beta,
                             const float* __restrict__ fcw, const float* __restrict__ fcb,
                             float* __restrict__ out)
{
  const int tid = threadIdx.x;
  const int wave = tid >> 6;
  const int lane = tid & 63;
  float A[16];
  float kp = 0.f;
#pragma unroll
  for (int j = 0; j < 16; ++j) {
    const int c = 16 * lane + j;
    float mu = sums[c] * (1.f / TT);
    float var = fmaxf(sums[HD + c] * (1.f / TT) - mu * mu, 0.f);
    float rs = rsqrtf(var + 1e-5f);
    float a = rs * gamma[c] * fcw[c];
    A[j] = a;
    kp += beta[c] * fcw[c] - mu * a;
  }
#pragma unroll
  for (int m = 32; m >= 1; m >>= 1) kp += __shfl_xor(kp, m);
  const float K = kp + fcb[0];
  const int tbase = (blockIdx.x * 4 + wave) * 16;
  for (int mm = 0; mm < 16; ++mm) {
    const int t = tbase + mm;
    const unsigned* p = h2u + (size_t)(t + 1) * 512 + 8 * lane;
    float d = 0.f;
#pragma unroll
    for (int j = 0; j < 8; ++j) {
      h2_t hp = __builtin_bit_cast(h2_t, p[j]);
      d += (float)hp.x * A[2 * j] + (float)hp.y * A[2 * j + 1];
    }
#pragma unroll
    for (int m = 32; m >= 1; m >>= 1) d += __shfl_xor(d, m);
    if (lane == 0) out[t] = K + d;
  }
}

extern "C" void kernel_launch(void* const* d_in, const int* in_sizes, int n_in,
                              void* d_out, int out_size, void* d_ws, size_t ws_size,
                              hipStream_t stream) {
  const float* x    = (const float*)d_in[0];
  const float* wih0 = (const float*)d_in[1];
  const float* whh0 = (const float*)d_in[2];
  const float* bih0 = (const float*)d_in[3];
  const float* bhh0 = (const float*)d_in[4];
  const float* wih1 = (const float*)d_in[5];
  const float* whh1 = (const float*)d_in[6];
  const float* bih1 = (const float*)d_in[7];
  const float* bhh1 = (const float*)d_in[8];
  const float* gamma = (const float*)d_in[9];
  const float* beta  = (const float*)d_in[10];
  const float* fcw   = (const float*)d_in[11];
  const float* fcb   = (const float*)d_in[12];

  const size_t HIST = (size_t)(TT + 1) * HD * 2;   // 33,556,480 B per history
  u64* h1u = (u64*)d_ws;
  u64* h2u = (u64*)((char*)d_ws + HIST);
  float* sums = (float*)((char*)d_ws + 2 * HIST);

  // slot 0 = h[-1] = 0 ; slots 1..TT = f16 NaN sentinel (0x7F7F)
  hipMemsetAsync(h1u, 0, (size_t)HD * 2, stream);
  hipMemsetAsync((char*)h1u + HD * 2, 0x7F, (size_t)TT * HD * 2, stream);
  hipMemsetAsync(h2u, 0, (size_t)HD * 2, stream);
  hipMemsetAsync((char*)h2u + HD * 2, 0x7F, (size_t)TT * HD * 2, stream);

  gru_persistent<<<128, 256, 0, stream>>>(x, wih0, whh0, bih0, bhh0,
                                          wih1, whh1, bih1, bhh1,
                                          h1u, h2u, sums);
  fc_bn_kernel<<<256, 256, 0, stream>>>((const unsigned*)h2u, sums, gamma, beta, fcw, fcb,
                                        (float*)d_out);
}

// Round 9
// 40581.940 us; speedup vs baseline: 2.5792x; 2.1565x over previous
//
#include <hip/hip_runtime.h>

// GRUModel: 2-layer GRU (T=16384, IN=512, H=1024) + BatchNorm(train) + FC(H->1)
//
// Persistent kernel, 128 blocks (64 layer0 + 64 layer1), 4 waves each; every
// wave owns 4 contiguous channels end-to-end (weights in VGPRs as f16 pairs,
// v_dot2_f32_f16). Wave-local butterfly reduction, gates computed redundantly
// in all lanes, one atomic u64 store per wave (4 channels packed f16).
// Cross-block exchange via AGENT-scope relaxed atomics on ws; consumers poll
// u64 granules against the f16-NaN sentinel 0x7F7F7F7F (memset 0x7F).
//
// ROUND-9. Law from R4-R8 (all regressed): dur tracks coherent-path spin
// ISSUE VOLUME; baseline spin FORM and PLACEMENT are a local optimum.
// Untried lever: cut the number of CONCURRENTLY SPINNING WAVES. Baseline has
// all 4 waves of each L1 block redundantly spinning on the same 2KB h2
// vector (256 waves on the hottest lines). Now only WAVE 0 of each L1 block
// runs the h2 spin (baseline form, baseline placement); waves 1-3 PARK at a
// __syncthreads (parked waves issue no memory ops - a perfect throttle) and
// receive the data via a 4KB double-buffered LDS slab. 4x cut in hot-vector
// spin traffic. Producers, granule layout, L0, and both h1 polls are
// byte-identical to the 53.6ms baseline. Cost: waves 1-3 see data ~150ns
// after wave0's detect (LDS write + barrier + LDS read; 16-way b128 LDS
// conflict ~50ns is accepted for layout simplicity).

#define TT 16384
#define IND 512
#define HD 1024

typedef _Float16 h2_t __attribute__((ext_vector_type(2)));
typedef unsigned long long u64;

static __device__ __forceinline__ float fdot2f(h2_t a, h2_t b, float c) {
  return __builtin_amdgcn_fdot2(a, b, c, false);
}
static __device__ __forceinline__ h2_t cvt2(float a, float b) {
  h2_t r; r.x = (_Float16)a; r.y = (_Float16)b; return r;
}
static __device__ __forceinline__ float sigm(float v) { return 1.f / (1.f + __expf(-v)); }
static __device__ __forceinline__ float tanh_f(float v) {
  v = fminf(fmaxf(v, -15.f), 15.f);
  float e = __expf(2.f * v);
  return (e - 1.f) / (e + 1.f);
}

// Reduce 4 per-lane partials across 64 lanes. Returns (R,Z,Nx,Nh) totals in
// all lanes. 11 DS ops instead of 24 (pair-merge butterfly).
static __device__ __forceinline__ float4 reduce4(float aR, float aZ, float aNx,
                                                 float aNh, int lane) {
  const bool s1 = lane & 1;
  float x1 = s1 ? aZ : aR, y1 = s1 ? aR : aZ;
  x1 += __shfl_xor(y1, 1);
  float x2 = s1 ? aNh : aNx, y2 = s1 ? aNx : aNh;
  x2 += __shfl_xor(y2, 1);
  const bool s2 = lane & 2;
  float z = s2 ? x2 : x1, w = s2 ? x1 : x2;
  z += __shfl_xor(w, 2);
  z += __shfl_xor(z, 4);
  z += __shfl_xor(z, 8);
  z += __shfl_xor(z, 16);
  z += __shfl_xor(z, 32);
  // lane%4==0 holds sumR, ==1 sumZ, ==2 sumNx, ==3 sumNh
  return make_float4(__shfl(z, 0), __shfl(z, 1), __shfl(z, 2), __shfl(z, 3));
}

static __device__ __forceinline__ u64 pack4(float h0, float h1,
                                            float h2, float h3) {
  unsigned lo = (unsigned)__builtin_bit_cast(unsigned short, (_Float16)h0) |
                ((unsigned)__builtin_bit_cast(unsigned short, (_Float16)h1) << 16);
  unsigned hi = (unsigned)__builtin_bit_cast(unsigned short, (_Float16)h2) |
                ((unsigned)__builtin_bit_cast(unsigned short, (_Float16)h3) << 16);
  return (u64)lo | ((u64)hi << 32);
}

static __device__ __forceinline__ void unpack8(const u64 hv[4], h2_t hh[8]) {
#pragma unroll
  for (int i = 0; i < 4; ++i) {
    hh[2 * i]     = __builtin_bit_cast(h2_t, (unsigned)hv[i]);
    hh[2 * i + 1] = __builtin_bit_cast(h2_t, (unsigned)(hv[i] >> 32));
  }
}

__launch_bounds__(256, 1)
__global__ void gru_persistent(
    const float* __restrict__ x,
    const float* __restrict__ wih0, const float* __restrict__ whh0,
    const float* __restrict__ bih0, const float* __restrict__ bhh0,
    const float* __restrict__ wih1, const float* __restrict__ whh1,
    const float* __restrict__ bih1, const float* __restrict__ bhh1,
    u64* h1u, u64* h2u, float* sums)
{
  __shared__ u64 h2b[2][256];   // double-buffered h2 broadcast (L1 blocks)
  const int bid = blockIdx.x;
  const int tid = threadIdx.x;
  const int wave = tid >> 6;
  const int lane = tid & 63;

  if (bid < 64) {
    // ------------- layer 0 : byte-identical to the 53.6ms baseline ---------
    const int ch = bid * 16 + wave * 4;
    h2_t Wx[4][3][4];   // x-part: 8 f16 per gate per channel
    h2_t Wh[4][3][8];   // h-part: 16 f16 per gate per channel
    float bRv[4], bZv[4], bNxv[4], bNhv[4];
#pragma unroll
    for (int cc = 0; cc < 4; ++cc) {
      const int c = ch + cc;
#pragma unroll
      for (int g = 0; g < 3; ++g) {
        const float* pr = wih0 + (size_t)(g * HD + c) * IND + 8 * lane;
#pragma unroll
        for (int j = 0; j < 4; ++j) Wx[cc][g][j] = cvt2(pr[2 * j], pr[2 * j + 1]);
        const float* ph = whh0 + (size_t)(g * HD + c) * HD + 16 * lane;
#pragma unroll
        for (int j = 0; j < 8; ++j) Wh[cc][g][j] = cvt2(ph[2 * j], ph[2 * j + 1]);
      }
      bRv[cc]  = bih0[c] + bhh0[c];
      bZv[cc]  = bih0[HD + c] + bhh0[HD + c];
      bNxv[cc] = bih0[2 * HD + c];
      bNhv[cc] = bhh0[2 * HD + c];
    }
    float hprev[4] = {0.f, 0.f, 0.f, 0.f};
    // software-pipelined x row
    const float* px0 = x + 8 * lane;
    float4 xa = *(const float4*)px0;
    float4 xb = *(const float4*)(px0 + 4);
    for (int t = 0; t < TT; ++t) {
      h2_t xv[4];
      xv[0] = cvt2(xa.x, xa.y); xv[1] = cvt2(xa.z, xa.w);
      xv[2] = cvt2(xb.x, xb.y); xv[3] = cvt2(xb.z, xb.w);
      if (t + 1 < TT) {
        const float* pn = x + (size_t)(t + 1) * IND + 8 * lane;
        xa = *(const float4*)pn;
        xb = *(const float4*)(pn + 4);
      }
      // x-part partials (off critical path)
      float aR[4], aZ[4], aNx[4], aNh[4];
#pragma unroll
      for (int cc = 0; cc < 4; ++cc) {
        float r = 0.f, z = 0.f, n = 0.f;
#pragma unroll
        for (int j = 0; j < 4; ++j) {
          r = fdot2f(Wx[cc][0][j], xv[j], r);
          z = fdot2f(Wx[cc][1][j], xv[j], z);
          n = fdot2f(Wx[cc][2][j], xv[j], n);
        }
        aR[cc] = r; aZ[cc] = z; aNx[cc] = n; aNh[cc] = 0.f;
      }
      // poll h1[t-1] (slot t; slot 0 pre-zeroed) — baseline form
      const u64* p1 = h1u + (size_t)t * 256 + 4 * lane;
      u64 hv[4];
      bool ok;
      do {
        ok = true;
#pragma unroll
        for (int i = 0; i < 4; ++i) {
          hv[i] = __hip_atomic_load(p1 + i, __ATOMIC_RELAXED, __HIP_MEMORY_SCOPE_AGENT);
          ok = ok & ((unsigned)hv[i] != 0x7F7F7F7Fu);
        }
      } while (__any(!ok));
      h2_t hh[8];
      unpack8(hv, hh);
#pragma unroll
      for (int cc = 0; cc < 4; ++cc) {
        float r = aR[cc], z = aZ[cc], n = aNh[cc];
#pragma unroll
        for (int j = 0; j < 8; ++j) {
          r = fdot2f(Wh[cc][0][j], hh[j], r);
          z = fdot2f(Wh[cc][1][j], hh[j], z);
          n = fdot2f(Wh[cc][2][j], hh[j], n);
        }
        aR[cc] = r; aZ[cc] = z; aNh[cc] = n;
      }
      float hn[4];
#pragma unroll
      for (int cc = 0; cc < 4; ++cc) {
        float4 s = reduce4(aR[cc], aZ[cc], aNx[cc], aNh[cc], lane);
        float r = sigm(s.x + bRv[cc]);
        float zz = sigm(s.y + bZv[cc]);
        float n = tanh_f(s.z + bNxv[cc] + r * (s.w + bNhv[cc]));
        hn[cc] = (1.f - zz) * n + zz * hprev[cc];
        hprev[cc] = hn[cc];
      }
      if (lane == 0) {
        u64 pk = pack4(hn[0], hn[1], hn[2], hn[3]);
        __hip_atomic_store(h1u + (size_t)(t + 1) * 256 + (ch >> 2), pk,
                           __ATOMIC_RELAXED, __HIP_MEMORY_SCOPE_AGENT);
      }
    }
  } else {
    // ---------------- layer 1 : wave owns channels ch..ch+3 ----------------
    const int ch = (bid - 64) * 16 + wave * 4;
    // parts: 0=r_ih 1=r_hh 2=z_ih 3=z_hh 4=n_ih 5=n_hh ; 16-f16 slice each
    h2_t W[4][6][8];
    float bRv[4], bZv[4], bNxv[4], bNhv[4];
#pragma unroll
    for (int cc = 0; cc < 4; ++cc) {
      const int c = ch + cc;
#pragma unroll
      for (int g = 0; g < 3; ++g) {
        const float* pi = wih1 + (size_t)(g * HD + c) * HD + 16 * lane;
        const float* ph = whh1 + (size_t)(g * HD + c) * HD + 16 * lane;
#pragma unroll
        for (int j = 0; j < 8; ++j) {
          W[cc][2 * g][j]     = cvt2(pi[2 * j], pi[2 * j + 1]);
          W[cc][2 * g + 1][j] = cvt2(ph[2 * j], ph[2 * j + 1]);
        }
      }
      bRv[cc]  = bih1[c] + bhh1[c];
      bZv[cc]  = bih1[HD + c] + bhh1[HD + c];
      bNxv[cc] = bih1[2 * HD + c];
      bNhv[cc] = bhh1[2 * HD + c];
    }
    float hprev[4] = {0.f, 0.f, 0.f, 0.f};
    float ssum[4] = {0.f, 0.f, 0.f, 0.f};
    float ssq[4] = {0.f, 0.f, 0.f, 0.f};
    for (int t = 1; t <= TT; ++t) {
      // poll h1[t-1] (slot t) — baseline per-wave form (usually 1 iteration;
      // keeps waves decoupled during the off-path phase)
      const u64* p1 = h1u + (size_t)t * 256 + 4 * lane;
      u64 va[4];
      bool ok;
      do {
        ok = true;
#pragma unroll
        for (int i = 0; i < 4; ++i) {
          va[i] = __hip_atomic_load(p1 + i, __ATOMIC_RELAXED, __HIP_MEMORY_SCOPE_AGENT);
          ok = ok & ((unsigned)va[i] != 0x7F7F7F7Fu);
        }
      } while (__any(!ok));
      h2_t g1[8];
      unpack8(va, g1);
      float aR[4], aZ[4], aNx[4], aNh[4];
#pragma unroll
      for (int cc = 0; cc < 4; ++cc) {
        float r = 0.f, z = 0.f, n = 0.f;
#pragma unroll
        for (int j = 0; j < 8; ++j) {
          r = fdot2f(W[cc][0][j], g1[j], r);
          z = fdot2f(W[cc][2][j], g1[j], z);
          n = fdot2f(W[cc][4][j], g1[j], n);
        }
        aR[cc] = r; aZ[cc] = z; aNx[cc] = n; aNh[cc] = 0.f;
      }
      // h2[t-2] (slot t-1): SINGLE-WAVE spin (baseline form/placement) +
      // LDS broadcast. Waves 1-3 park at the barrier (no memory traffic).
      u64 vb[4];
      if (wave == 0) {
        const u64* p2 = h2u + (size_t)(t - 1) * 256 + 4 * lane;
        do {
          ok = true;
#pragma unroll
          for (int i = 0; i < 4; ++i) {
            vb[i] = __hip_atomic_load(p2 + i, __ATOMIC_RELAXED, __HIP_MEMORY_SCOPE_AGENT);
            ok = ok & ((unsigned)vb[i] != 0x7F7F7F7Fu);
          }
        } while (__any(!ok));
#pragma unroll
        for (int i = 0; i < 4; ++i) h2b[t & 1][4 * lane + i] = vb[i];
      }
      __syncthreads();
      if (wave != 0) {
#pragma unroll
        for (int i = 0; i < 4; ++i) vb[i] = h2b[t & 1][4 * lane + i];
      }
      h2_t g2[8];
      unpack8(vb, g2);
#pragma unroll
      for (int cc = 0; cc < 4; ++cc) {
        float r = aR[cc], z = aZ[cc], n = aNh[cc];
#pragma unroll
        for (int j = 0; j < 8; ++j) {
          r = fdot2f(W[cc][1][j], g2[j], r);
          z = fdot2f(W[cc][3][j], g2[j], z);
          n = fdot2f(W[cc][5][j], g2[j], n);
        }
        aR[cc] = r; aZ[cc] = z; aNh[cc] = n;
      }
      float hn[4];
#pragma unroll
      for (int cc = 0; cc < 4; ++cc) {
        float4 s = reduce4(aR[cc], aZ[cc], aNx[cc], aNh[cc], lane);
        float r = sigm(s.x + bRv[cc]);
        float zz = sigm(s.y + bZv[cc]);
        float n = tanh_f(s.z + bNxv[cc] + r * (s.w + bNhv[cc]));
        hn[cc] = (1.f - zz) * n + zz * hprev[cc];
        hprev[cc] = hn[cc];
        ssum[cc] += hn[cc];
        ssq[cc] += hn[cc] * hn[cc];
      }
      if (lane == 0) {
        u64 pk = pack4(hn[0], hn[1], hn[2], hn[3]);
        __hip_atomic_store(h2u + (size_t)t * 256 + (ch >> 2), pk,
                           __ATOMIC_RELAXED, __HIP_MEMORY_SCOPE_AGENT);
      }
    }
    if (lane == 0) {
#pragma unroll
      for (int cc = 0; cc < 4; ++cc) {
        sums[ch + cc] = ssum[cc];
        sums[HD + ch + cc] = ssq[cc];
      }
    }
  }
}

// y[t] = K + sum_c h2[t,c]*A[c];  A = rsqrt(var+eps)*gamma*fc_w,
// K = fc_b + sum_c (beta*fc_w - mu*A)
__launch_bounds__(256)
__global__ void fc_bn_kernel(const unsigned* __restrict__ h2u, const float* __restrict__ sums,
                             const float* __restrict__ gamma, const float* __restrict__ beta,
                             const float* __restrict__ fcw, const float* __restrict__ fcb,
                             float* __restrict__ out)
{
  const int tid = threadIdx.x;
  const int wave = tid >> 6;
  const int lane = tid & 63;
  float A[16];
  float kp = 0.f;
#pragma unroll
  for (int j = 0; j < 16; ++j) {
    const int c = 16 * lane + j;
    float mu = sums[c] * (1.f / TT);
    float var = fmaxf(sums[HD + c] * (1.f / TT) - mu * mu, 0.f);
    float rs = rsqrtf(var + 1e-5f);
    float a = rs * gamma[c] * fcw[c];
    A[j] = a;
    kp += beta[c] * fcw[c] - mu * a;
  }
#pragma unroll
  for (int m = 32; m >= 1; m >>= 1) kp += __shfl_xor(kp, m);
  const float K = kp + fcb[0];
  const int tbase = (blockIdx.x * 4 + wave) * 16;
  for (int mm = 0; mm < 16; ++mm) {
    const int t = tbase + mm;
    const unsigned* p = h2u + (size_t)(t + 1) * 512 + 8 * lane;
    float d = 0.f;
#pragma unroll
    for (int j = 0; j < 8; ++j) {
      h2_t hp = __builtin_bit_cast(h2_t, p[j]);
      d += (float)hp.x * A[2 * j] + (float)hp.y * A[2 * j + 1];
    }
#pragma unroll
    for (int m = 32; m >= 1; m >>= 1) d += __shfl_xor(d, m);
    if (lane == 0) out[t] = K + d;
  }
}

extern "C" void kernel_launch(void* const* d_in, const int* in_sizes, int n_in,
                              void* d_out, int out_size, void* d_ws, size_t ws_size,
                              hipStream_t stream) {
  const float* x    = (const float*)d_in[0];
  const float* wih0 = (const float*)d_in[1];
  const float* whh0 = (const float*)d_in[2];
  const float* bih0 = (const float*)d_in[3];
  const float* bhh0 = (const float*)d_in[4];
  const float* wih1 = (const float*)d_in[5];
  const float* whh1 = (const float*)d_in[6];
  const float* bih1 = (const float*)d_in[7];
  const float* bhh1 = (const float*)d_in[8];
  const float* gamma = (const float*)d_in[9];
  const float* beta  = (const float*)d_in[10];
  const float* fcw   = (const float*)d_in[11];
  const float* fcb   = (const float*)d_in[12];

  const size_t HIST = (size_t)(TT + 1) * HD * 2;   // 33,556,480 B per history
  u64* h1u = (u64*)d_ws;
  u64* h2u = (u64*)((char*)d_ws + HIST);
  float* sums = (float*)((char*)d_ws + 2 * HIST);

  // slot 0 = h[-1] = 0 ; slots 1..TT = f16 NaN sentinel (0x7F7F)
  hipMemsetAsync(h1u, 0, (size_t)HD * 2, stream);
  hipMemsetAsync((char*)h1u + HD * 2, 0x7F, (size_t)TT * HD * 2, stream);
  hipMemsetAsync(h2u, 0, (size_t)HD * 2, stream);
  hipMemsetAsync((char*)h2u + HD * 2, 0x7F, (size_t)TT * HD * 2, stream);

  gru_persistent<<<128, 256, 0, stream>>>(x, wih0, whh0, bih0, bhh0,
                                          wih1, whh1, bih1, bhh1,
                                          h1u, h2u, sums);
  fc_bn_kernel<<<256, 256, 0, stream>>>((const unsigned*)h2u, sums, gamma, beta, fcw, fcb,
                                        (float*)d_out);
}

// Round 10
// 39490.070 us; speedup vs baseline: 2.6505x; 1.0276x over previous
//
#include <hip/hip_runtime.h>

// GRUModel: 2-layer GRU (T=16384, IN=512, H=1024) + BatchNorm(train) + FC(H->1)
//
// Persistent kernel, 128 blocks (64 layer0 + 64 layer1), 4 waves each; every
// wave owns 4 contiguous channels end-to-end (weights in VGPRs as f16 pairs,
// v_dot2_f32_f16). Wave-local butterfly reduction, gates computed redundantly
// in all lanes, one atomic u64 store per wave (4 channels packed f16).
// Cross-block exchange via AGENT-scope relaxed atomics on ws; consumers poll
// u64 granules against the f16-NaN sentinel 0x7F7F7F7F (memset 0x7F).
//
// CONFIRMED LAW (R4-R9): dur tracks coherent-path spin ISSUE VOLUME. R9 cut
// the h2 spin population 4x (single-wave spin + park-at-barrier + LDS
// broadcast): 53.6 -> 40.6ms, FETCH 720 -> 490MB. R10 mirrors the exact same
// pattern onto LAYER 0's h1 spin (the largest remaining population: 256
// waves spinning long on their own producer convoy):
//   L0: wave 0 runs the baseline-form h1 spin at baseline placement (after
//       the x-dots); waves 1-3 park at __syncthreads (zero memory traffic);
//       broadcast via a second 4KB double-buffered LDS slab.
// L1 is byte-identical to R9 (h1 poll per-wave usually-ready; h2 spin
// single-wave + broadcast). Producers and granule layout unchanged.
// LDS double-buffer safety: writer reuses buf[b] at t+2 only after passing
// barrier t+1, which requires all readers of buf[b]@t to have finished.

#define TT 16384
#define IND 512
#define HD 1024

typedef _Float16 h2_t __attribute__((ext_vector_type(2)));
typedef unsigned long long u64;

static __device__ __forceinline__ float fdot2f(h2_t a, h2_t b, float c) {
  return __builtin_amdgcn_fdot2(a, b, c, false);
}
static __device__ __forceinline__ h2_t cvt2(float a, float b) {
  h2_t r; r.x = (_Float16)a; r.y = (_Float16)b; return r;
}
static __device__ __forceinline__ float sigm(float v) { return 1.f / (1.f + __expf(-v)); }
static __device__ __forceinline__ float tanh_f(float v) {
  v = fminf(fmaxf(v, -15.f), 15.f);
  float e = __expf(2.f * v);
  return (e - 1.f) / (e + 1.f);
}

// Reduce 4 per-lane partials across 64 lanes. Returns (R,Z,Nx,Nh) totals in
// all lanes. 11 DS ops instead of 24 (pair-merge butterfly).
static __device__ __forceinline__ float4 reduce4(float aR, float aZ, float aNx,
                                                 float aNh, int lane) {
  const bool s1 = lane & 1;
  float x1 = s1 ? aZ : aR, y1 = s1 ? aR : aZ;
  x1 += __shfl_xor(y1, 1);
  float x2 = s1 ? aNh : aNx, y2 = s1 ? aNx : aNh;
  x2 += __shfl_xor(y2, 1);
  const bool s2 = lane & 2;
  float z = s2 ? x2 : x1, w = s2 ? x1 : x2;
  z += __shfl_xor(w, 2);
  z += __shfl_xor(z, 4);
  z += __shfl_xor(z, 8);
  z += __shfl_xor(z, 16);
  z += __shfl_xor(z, 32);
  // lane%4==0 holds sumR, ==1 sumZ, ==2 sumNx, ==3 sumNh
  return make_float4(__shfl(z, 0), __shfl(z, 1), __shfl(z, 2), __shfl(z, 3));
}

static __device__ __forceinline__ u64 pack4(float h0, float h1,
                                            float h2, float h3) {
  unsigned lo = (unsigned)__builtin_bit_cast(unsigned short, (_Float16)h0) |
                ((unsigned)__builtin_bit_cast(unsigned short, (_Float16)h1) << 16);
  unsigned hi = (unsigned)__builtin_bit_cast(unsigned short, (_Float16)h2) |
                ((unsigned)__builtin_bit_cast(unsigned short, (_Float16)h3) << 16);
  return (u64)lo | ((u64)hi << 32);
}

static __device__ __forceinline__ void unpack8(const u64 hv[4], h2_t hh[8]) {
#pragma unroll
  for (int i = 0; i < 4; ++i) {
    hh[2 * i]     = __builtin_bit_cast(h2_t, (unsigned)hv[i]);
    hh[2 * i + 1] = __builtin_bit_cast(h2_t, (unsigned)(hv[i] >> 32));
  }
}

__launch_bounds__(256, 1)
__global__ void gru_persistent(
    const float* __restrict__ x,
    const float* __restrict__ wih0, const float* __restrict__ whh0,
    const float* __restrict__ bih0, const float* __restrict__ bhh0,
    const float* __restrict__ wih1, const float* __restrict__ whh1,
    const float* __restrict__ bih1, const float* __restrict__ bhh1,
    u64* h1u, u64* h2u, float* sums)
{
  __shared__ u64 bcast[2][256];  // double-buffered broadcast slab (both layers)
  const int bid = blockIdx.x;
  const int tid = threadIdx.x;
  const int wave = tid >> 6;
  const int lane = tid & 63;

  if (bid < 64) {
    // ---------------- layer 0 : wave owns channels ch..ch+3 ----------------
    const int ch = bid * 16 + wave * 4;
    h2_t Wx[4][3][4];   // x-part: 8 f16 per gate per channel
    h2_t Wh[4][3][8];   // h-part: 16 f16 per gate per channel
    float bRv[4], bZv[4], bNxv[4], bNhv[4];
#pragma unroll
    for (int cc = 0; cc < 4; ++cc) {
      const int c = ch + cc;
#pragma unroll
      for (int g = 0; g < 3; ++g) {
        const float* pr = wih0 + (size_t)(g * HD + c) * IND + 8 * lane;
#pragma unroll
        for (int j = 0; j < 4; ++j) Wx[cc][g][j] = cvt2(pr[2 * j], pr[2 * j + 1]);
        const float* ph = whh0 + (size_t)(g * HD + c) * HD + 16 * lane;
#pragma unroll
        for (int j = 0; j < 8; ++j) Wh[cc][g][j] = cvt2(ph[2 * j], ph[2 * j + 1]);
      }
      bRv[cc]  = bih0[c] + bhh0[c];
      bZv[cc]  = bih0[HD + c] + bhh0[HD + c];
      bNxv[cc] = bih0[2 * HD + c];
      bNhv[cc] = bhh0[2 * HD + c];
    }
    float hprev[4] = {0.f, 0.f, 0.f, 0.f};
    // software-pipelined x row
    const float* px0 = x + 8 * lane;
    float4 xa = *(const float4*)px0;
    float4 xb = *(const float4*)(px0 + 4);
    for (int t = 0; t < TT; ++t) {
      h2_t xv[4];
      xv[0] = cvt2(xa.x, xa.y); xv[1] = cvt2(xa.z, xa.w);
      xv[2] = cvt2(xb.x, xb.y); xv[3] = cvt2(xb.z, xb.w);
      if (t + 1 < TT) {
        const float* pn = x + (size_t)(t + 1) * IND + 8 * lane;
        xa = *(const float4*)pn;
        xb = *(const float4*)(pn + 4);
      }
      // x-part partials (off critical path, all waves)
      float aR[4], aZ[4], aNx[4], aNh[4];
#pragma unroll
      for (int cc = 0; cc < 4; ++cc) {
        float r = 0.f, z = 0.f, n = 0.f;
#pragma unroll
        for (int j = 0; j < 4; ++j) {
          r = fdot2f(Wx[cc][0][j], xv[j], r);
          z = fdot2f(Wx[cc][1][j], xv[j], z);
          n = fdot2f(Wx[cc][2][j], xv[j], n);
        }
        aR[cc] = r; aZ[cc] = z; aNx[cc] = n; aNh[cc] = 0.f;
      }
      // h1[t-1] (slot t; slot 0 pre-zeroed): SINGLE-WAVE spin (baseline form
      // and placement) + LDS broadcast; waves 1-3 park at the barrier.
      u64 hv[4];
      bool ok;
      if (wave == 0) {
        const u64* p1 = h1u + (size_t)t * 256 + 4 * lane;
        do {
          ok = true;
#pragma unroll
          for (int i = 0; i < 4; ++i) {
            hv[i] = __hip_atomic_load(p1 + i, __ATOMIC_RELAXED, __HIP_MEMORY_SCOPE_AGENT);
            ok = ok & ((unsigned)hv[i] != 0x7F7F7F7Fu);
          }
        } while (__any(!ok));
#pragma unroll
        for (int i = 0; i < 4; ++i) bcast[t & 1][4 * lane + i] = hv[i];
      }
      __syncthreads();
      if (wave != 0) {
#pragma unroll
        for (int i = 0; i < 4; ++i) hv[i] = bcast[t & 1][4 * lane + i];
      }
      h2_t hh[8];
      unpack8(hv, hh);
#pragma unroll
      for (int cc = 0; cc < 4; ++cc) {
        float r = aR[cc], z = aZ[cc], n = aNh[cc];
#pragma unroll
        for (int j = 0; j < 8; ++j) {
          r = fdot2f(Wh[cc][0][j], hh[j], r);
          z = fdot2f(Wh[cc][1][j], hh[j], z);
          n = fdot2f(Wh[cc][2][j], hh[j], n);
        }
        aR[cc] = r; aZ[cc] = z; aNh[cc] = n;
      }
      float hn[4];
#pragma unroll
      for (int cc = 0; cc < 4; ++cc) {
        float4 s = reduce4(aR[cc], aZ[cc], aNx[cc], aNh[cc], lane);
        float r = sigm(s.x + bRv[cc]);
        float zz = sigm(s.y + bZv[cc]);
        float n = tanh_f(s.z + bNxv[cc] + r * (s.w + bNhv[cc]));
        hn[cc] = (1.f - zz) * n + zz * hprev[cc];
        hprev[cc] = hn[cc];
      }
      if (lane == 0) {
        u64 pk = pack4(hn[0], hn[1], hn[2], hn[3]);
        __hip_atomic_store(h1u + (size_t)(t + 1) * 256 + (ch >> 2), pk,
                           __ATOMIC_RELAXED, __HIP_MEMORY_SCOPE_AGENT);
      }
    }
  } else {
    // ------------- layer 1 : byte-identical to R9's winning form -----------
    const int ch = (bid - 64) * 16 + wave * 4;
    // parts: 0=r_ih 1=r_hh 2=z_ih 3=z_hh 4=n_ih 5=n_hh ; 16-f16 slice each
    h2_t W[4][6][8];
    float bRv[4], bZv[4], bNxv[4], bNhv[4];
#pragma unroll
    for (int cc = 0; cc < 4; ++cc) {
      const int c = ch + cc;
#pragma unroll
      for (int g = 0; g < 3; ++g) {
        const float* pi = wih1 + (size_t)(g * HD + c) * HD + 16 * lane;
        const float* ph = whh1 + (size_t)(g * HD + c) * HD + 16 * lane;
#pragma unroll
        for (int j = 0; j < 8; ++j) {
          W[cc][2 * g][j]     = cvt2(pi[2 * j], pi[2 * j + 1]);
          W[cc][2 * g + 1][j] = cvt2(ph[2 * j], ph[2 * j + 1]);
        }
      }
      bRv[cc]  = bih1[c] + bhh1[c];
      bZv[cc]  = bih1[HD + c] + bhh1[HD + c];
      bNxv[cc] = bih1[2 * HD + c];
      bNhv[cc] = bhh1[2 * HD + c];
    }
    float hprev[4] = {0.f, 0.f, 0.f, 0.f};
    float ssum[4] = {0.f, 0.f, 0.f, 0.f};
    float ssq[4] = {0.f, 0.f, 0.f, 0.f};
    for (int t = 1; t <= TT; ++t) {
      // poll h1[t-1] (slot t) — per-wave baseline form (usually 1 iteration)
      const u64* p1 = h1u + (size_t)t * 256 + 4 * lane;
      u64 va[4];
      bool ok;
      do {
        ok = true;
#pragma unroll
        for (int i = 0; i < 4; ++i) {
          va[i] = __hip_atomic_load(p1 + i, __ATOMIC_RELAXED, __HIP_MEMORY_SCOPE_AGENT);
          ok = ok & ((unsigned)va[i] != 0x7F7F7F7Fu);
        }
      } while (__any(!ok));
      h2_t g1[8];
      unpack8(va, g1);
      float aR[4], aZ[4], aNx[4], aNh[4];
#pragma unroll
      for (int cc = 0; cc < 4; ++cc) {
        float r = 0.f, z = 0.f, n = 0.f;
#pragma unroll
        for (int j = 0; j < 8; ++j) {
          r = fdot2f(W[cc][0][j], g1[j], r);
          z = fdot2f(W[cc][2][j], g1[j], z);
          n = fdot2f(W[cc][4][j], g1[j], n);
        }
        aR[cc] = r; aZ[cc] = z; aNx[cc] = n; aNh[cc] = 0.f;
      }
      // h2[t-2] (slot t-1): single-wave spin + LDS broadcast (R9 form)
      u64 vb[4];
      if (wave == 0) {
        const u64* p2 = h2u + (size_t)(t - 1) * 256 + 4 * lane;
        do {
          ok = true;
#pragma unroll
          for (int i = 0; i < 4; ++i) {
            vb[i] = __hip_atomic_load(p2 + i, __ATOMIC_RELAXED, __HIP_MEMORY_SCOPE_AGENT);
            ok = ok & ((unsigned)vb[i] != 0x7F7F7F7Fu);
          }
        } while (__any(!ok));
#pragma unroll
        for (int i = 0; i < 4; ++i) bcast[t & 1][4 * lane + i] = vb[i];
      }
      __syncthreads();
      if (wave != 0) {
#pragma unroll
        for (int i = 0; i < 4; ++i) vb[i] = bcast[t & 1][4 * lane + i];
      }
      h2_t g2[8];
      unpack8(vb, g2);
#pragma unroll
      for (int cc = 0; cc < 4; ++cc) {
        float r = aR[cc], z = aZ[cc], n = aNh[cc];
#pragma unroll
        for (int j = 0; j < 8; ++j) {
          r = fdot2f(W[cc][1][j], g2[j], r);
          z = fdot2f(W[cc][3][j], g2[j], z);
          n = fdot2f(W[cc][5][j], g2[j], n);
        }
        aR[cc] = r; aZ[cc] = z; aNh[cc] = n;
      }
      float hn[4];
#pragma unroll
      for (int cc = 0; cc < 4; ++cc) {
        float4 s = reduce4(aR[cc], aZ[cc], aNx[cc], aNh[cc], lane);
        float r = sigm(s.x + bRv[cc]);
        float zz = sigm(s.y + bZv[cc]);
        float n = tanh_f(s.z + bNxv[cc] + r * (s.w + bNhv[cc]));
        hn[cc] = (1.f - zz) * n + zz * hprev[cc];
        hprev[cc] = hn[cc];
        ssum[cc] += hn[cc];
        ssq[cc] += hn[cc] * hn[cc];
      }
      if (lane == 0) {
        u64 pk = pack4(hn[0], hn[1], hn[2], hn[3]);
        __hip_atomic_store(h2u + (size_t)t * 256 + (ch >> 2), pk,
                           __ATOMIC_RELAXED, __HIP_MEMORY_SCOPE_AGENT);
      }
    }
    if (lane == 0) {
#pragma unroll
      for (int cc = 0; cc < 4; ++cc) {
        sums[ch + cc] = ssum[cc];
        sums[HD + ch + cc] = ssq[cc];
      }
    }
  }
}

// y[t] = K + sum_c h2[t,c]*A[c];  A = rsqrt(var+eps)*gamma*fc_w,
// K = fc_b + sum_c (beta*fc_w - mu*A)
__launch_bounds__(256)
__global__ void fc_bn_kernel(const unsigned* __restrict__ h2u, const float* __restrict__ sums,
                             const float* __restrict__ gamma, const float* __restrict__ beta,
                             const float* __restrict__ fcw, const float* __restrict__ fcb,
                             float* __restrict__ out)
{
  const int tid = threadIdx.x;
  const int wave = tid >> 6;
  const int lane = tid & 63;
  float A[16];
  float kp = 0.f;
#pragma unroll
  for (int j = 0; j < 16; ++j) {
    const int c = 16 * lane + j;
    float mu = sums[c] * (1.f / TT);
    float var = fmaxf(sums[HD + c] * (1.f / TT) - mu * mu, 0.f);
    float rs = rsqrtf(var + 1e-5f);
    float a = rs * gamma[c] * fcw[c];
    A[j] = a;
    kp += beta[c] * fcw[c] - mu * a;
  }
#pragma unroll
  for (int m = 32; m >= 1; m >>= 1) kp += __shfl_xor(kp, m);
  const float K = kp + fcb[0];
  const int tbase = (blockIdx.x * 4 + wave) * 16;
  for (int mm = 0; mm < 16; ++mm) {
    const int t = tbase + mm;
    const unsigned* p = h2u + (size_t)(t + 1) * 512 + 8 * lane;
    float d = 0.f;
#pragma unroll
    for (int j = 0; j < 8; ++j) {
      h2_t hp = __builtin_bit_cast(h2_t, p[j]);
      d += (float)hp.x * A[2 * j] + (float)hp.y * A[2 * j + 1];
    }
#pragma unroll
    for (int m = 32; m >= 1; m >>= 1) d += __shfl_xor(d, m);
    if (lane == 0) out[t] = K + d;
  }
}

extern "C" void kernel_launch(void* const* d_in, const int* in_sizes, int n_in,
                              void* d_out, int out_size, void* d_ws, size_t ws_size,
                              hipStream_t stream) {
  const float* x    = (const float*)d_in[0];
  const float* wih0 = (const float*)d_in[1];
  const float* whh0 = (const float*)d_in[2];
  const float* bih0 = (const float*)d_in[3];
  const float* bhh0 = (const float*)d_in[4];
  const float* wih1 = (const float*)d_in[5];
  const float* whh1 = (const float*)d_in[6];
  const float* bih1 = (const float*)d_in[7];
  const float* bhh1 = (const float*)d_in[8];
  const float* gamma = (const float*)d_in[9];
  const float* beta  = (const float*)d_in[10];
  const float* fcw   = (const float*)d_in[11];
  const float* fcb   = (const float*)d_in[12];

  const size_t HIST = (size_t)(TT + 1) * HD * 2;   // 33,556,480 B per history
  u64* h1u = (u64*)d_ws;
  u64* h2u = (u64*)((char*)d_ws + HIST);
  float* sums = (float*)((char*)d_ws + 2 * HIST);

  // slot 0 = h[-1] = 0 ; slots 1..TT = f16 NaN sentinel (0x7F7F)
  hipMemsetAsync(h1u, 0, (size_t)HD * 2, stream);
  hipMemsetAsync((char*)h1u + HD * 2, 0x7F, (size_t)TT * HD * 2, stream);
  hipMemsetAsync(h2u, 0, (size_t)HD * 2, stream);
  hipMemsetAsync((char*)h2u + HD * 2, 0x7F, (size_t)TT * HD * 2, stream);

  gru_persistent<<<128, 256, 0, stream>>>(x, wih0, whh0, bih0, bhh0,
                                          wih1, whh1, bih1, bhh1,
                                          h1u, h2u, sums);
  fc_bn_kernel<<<256, 256, 0, stream>>>((const unsigned*)h2u, sums, gamma, beta, fcw, fcb,
                                        (float*)d_out);
}